// Round 23
// baseline (86.462 us; speedup 1.0000x reference)
//
#include <hip/hip_runtime.h>
#include <math.h>

#define S_DIM 256
#define D_DIM 128
#define NHEAD 4
#define HD_DIM 32
#define SEC 2097152   // 65536 tokens * 32 (shorts per section)

typedef __attribute__((ext_vector_type(8))) short bf16x8;
typedef __attribute__((ext_vector_type(4))) float floatx4;

#define MFMA(a, b, c) __builtin_amdgcn_mfma_f32_16x16x32_bf16(a, b, c, 0, 0, 0)

#define LOG2E 1.4426950408889634f

__device__ inline float exp2_hw(float x) {        // v_exp_f32 = 2^x
    float r;
    asm("v_exp_f32 %0, %1" : "=v"(r) : "v"(x));
    return r;
}
__device__ inline float rcp_hw(float x) {         // v_rcp_f32 ~1ulp
    float r;
    asm("v_rcp_f32 %0, %1" : "=v"(r) : "v"(x));
    return r;
}
__device__ inline unsigned int cvt_pk_bf16(float lo, float hi) {  // RNE pack
    unsigned int r;
    asm("v_cvt_pk_bf16_f32 %0, %1, %2" : "=v"(r) : "v"(lo), "v"(hi));
    return r;
}
__device__ inline unsigned short f2bf(float v) {
    return (unsigned short)(cvt_pk_bf16(v, v) & 0xffffu);
}
__device__ inline float bf2f(unsigned short s) {
    return __uint_as_float(((unsigned int)s) << 16);
}

// ---------------------------------------------------------------------------
// Kernel 1: weight convert to bf16 (verbatim).
// ---------------------------------------------------------------------------
__global__ __launch_bounds__(256) void wconv_kernel(
        const float* __restrict__ wq, const float* __restrict__ wk,
        const float* __restrict__ wv, const float* __restrict__ wg,
        const float* __restrict__ wo,
        unsigned short* __restrict__ wcat16, unsigned short* __restrict__ wo16) {
    int idx = blockIdx.x * 256 + threadIdx.x;
    if (idx < 65536) {
        int r = idx >> 7, c = idx & 127;
        float v;
        if (r < 128)      v = wq[idx] * (0.17677669529663687f * LOG2E);
        else if (r < 256) v = wk[(r - 128) * 128 + c];
        else if (r < 384) v = wv[(r - 256) * 128 + c];
        else              v = wg[(r - 384) * 128 + c];
        wcat16[idx] = f2bf(v);
    }
    if (idx < 16384) wo16[idx] = f2bf(wo[idx]);
}

// ---------------------------------------------------------------------------
// Kernel 2: fused LN + projection GEMM + fp32 bias GEMV.
// R19 math, ROW-SPLIT for TLP: 2048 blocks x 512 threads, 32-row tile,
// 8 waves x 64 cols, acc[2][4]. No traffic duplication (unlike the R16/17
// column split). LN: 16 threads/row (shfl tree 1,2,4,8). Epilogue =
// proven LDS-transpose wide stores to head-blocked qkvg2.
// ---------------------------------------------------------------------------
#define GP 136
#define XS 68   // transpose scratch row stride (shorts)
__global__ __launch_bounds__(512, 4) void proj_gemm(
        const float* __restrict__ x,
        const float* __restrict__ ln_w, const float* __restrict__ ln_b,
        const float* __restrict__ w_bias,
        const unsigned short* __restrict__ wcat16,
        unsigned short* __restrict__ qkvg, float* __restrict__ bias_t) {
    __shared__ __align__(16) unsigned short As[8 * 16 * XS];  // 8704 >= 32*GP
    int mt = blockIdx.x;          // 32-row tile index
    int t = threadIdx.x;          // 0..511
    int r = t >> 4, c0 = (t & 15) * 8;
    {   // LN staging: 16 threads per row, 8 cols each
        const float* xr = x + (size_t)(mt * 32 + r) * 128 + c0;
        float4 xv[2];
        float s = 0.f, sq = 0.f;
        #pragma unroll
        for (int i = 0; i < 2; ++i) {
            xv[i] = *reinterpret_cast<const float4*>(xr + i * 4);
            s += (xv[i].x + xv[i].y) + (xv[i].z + xv[i].w);
            sq += (xv[i].x * xv[i].x + xv[i].y * xv[i].y)
                + (xv[i].z * xv[i].z + xv[i].w * xv[i].w);
        }
        s += __shfl_xor(s, 1);  s += __shfl_xor(s, 2);
        s += __shfl_xor(s, 4);  s += __shfl_xor(s, 8);
        sq += __shfl_xor(sq, 1); sq += __shfl_xor(sq, 2);
        sq += __shfl_xor(sq, 4); sq += __shfl_xor(sq, 8);
        float mu = s * (1.0f / 128.0f);
        float rstd = rsqrtf(sq * (1.0f / 128.0f) - mu * mu + 1e-5f);
        float pb[4] = {0.f, 0.f, 0.f, 0.f};
        #pragma unroll
        for (int i = 0; i < 2; ++i) {
            float4 wv4 = *reinterpret_cast<const float4*>(ln_w + c0 + i * 4);
            float4 bv4 = *reinterpret_cast<const float4*>(ln_b + c0 + i * 4);
            float h0 = (xv[i].x - mu) * rstd * wv4.x + bv4.x;
            float h1 = (xv[i].y - mu) * rstd * wv4.y + bv4.y;
            float h2 = (xv[i].z - mu) * rstd * wv4.z + bv4.z;
            float h3 = (xv[i].w - mu) * rstd * wv4.w + bv4.w;
            unsigned int* dst = reinterpret_cast<unsigned int*>(&As[r * GP + c0 + i * 4]);
            dst[0] = cvt_pk_bf16(h0, h1);
            dst[1] = cvt_pk_bf16(h2, h3);
            #pragma unroll
            for (int hh = 0; hh < 4; ++hh) {
                float4 wb4 = *reinterpret_cast<const float4*>(w_bias + hh * 128 + c0 + i * 4);
                pb[hh] += (h0 * wb4.x + h1 * wb4.y) + (h2 * wb4.z + h3 * wb4.w);
            }
        }
        #pragma unroll
        for (int hh = 0; hh < 4; ++hh) {
            pb[hh] += __shfl_xor(pb[hh], 1);
            pb[hh] += __shfl_xor(pb[hh], 2);
            pb[hh] += __shfl_xor(pb[hh], 4);
            pb[hh] += __shfl_xor(pb[hh], 8);
        }
        if ((t & 15) == 0) {
            int m = mt * 32 + r;
            int q = m >> 8;
            int k = m & 255;
            #pragma unroll
            for (int hh = 0; hh < 4; ++hh)
                bias_t[hh * 65536 + (k >> 2) * 1024 + q * 4 + (k & 3)] = pb[hh] * LOG2E;
        }
    }
    __syncthreads();
    int wave = t >> 6, lane = t & 63;
    int lg = lane >> 4, lr = lane & 15;
    int n0 = wave * 64;                    // wave owns cols [n0, n0+64)
    floatx4 acc[2][4] = {};
    #pragma unroll
    for (int ks = 0; ks < 4; ++ks) {
        bf16x8 a[2], b[4];
        #pragma unroll
        for (int j = 0; j < 4; ++j)
            b[j] = *reinterpret_cast<const bf16x8*>(
                wcat16 + (size_t)(n0 + j * 16 + lr) * 128 + ks * 32 + lg * 8);
        #pragma unroll
        for (int i = 0; i < 2; ++i)
            a[i] = *reinterpret_cast<const bf16x8*>(&As[(i * 16 + lr) * GP + ks * 32 + lg * 8]);
        #pragma unroll
        for (int i = 0; i < 2; ++i)
            #pragma unroll
            for (int j = 0; j < 4; ++j)
                acc[i][j] = MFMA(a[i], b[j], acc[i][j]);
    }
    __syncthreads();                       // all waves done reading As
    bool is_g = (wave >= 6);               // cols 384..511 -> type 3
    unsigned short* xs = As + wave * (16 * XS);   // per-wave scratch
    int rrow = lane >> 3, rc8 = (lane & 7) * 8;   // read/store mapping
    int col = n0 + rc8;                    // 512-col space
    int sec = (col >> 7) * 4 + ((col >> 5) & 3);  // type*4 + head
    int dd  = col & 31;                    // d offset within head
    #pragma unroll
    for (int i = 0; i < 2; ++i) {
        #pragma unroll
        for (int j = 0; j < 4; ++j)
            #pragma unroll
            for (int rr = 0; rr < 4; ++rr) {
                float v = acc[i][j][rr];
                if (is_g) v = rcp_hw(1.0f + exp2_hw(-LOG2E * v));
                xs[(lg * 4 + rr) * XS + j * 16 + lr] = f2bf(v);
            }
        #pragma unroll
        for (int p = 0; p < 2; ++p) {
            int row = p * 8 + rrow;
            uint2 lo = *reinterpret_cast<const uint2*>(&xs[row * XS + rc8]);
            uint2 hi = *reinterpret_cast<const uint2*>(&xs[row * XS + rc8 + 4]);
            uint4 vv = {lo.x, lo.y, hi.x, hi.y};
            size_t m = (size_t)(mt * 32 + i * 16 + row);
            *reinterpret_cast<uint4*>(
                &qkvg[(size_t)sec * SEC + m * 32 + dd]) = vv;
        }
    }
}

// ---------------------------------------------------------------------------
// Kernel 3: attention (R19-exact, head-blocked qkvg2 reads, plain
// launch_bounds(256) -- free allocation, VGPR 116, no spill).
// ---------------------------------------------------------------------------
#define KP 40    // k_lds row stride (bf16)
#define VP 260   // vT row stride (bf16)
__global__ __launch_bounds__(256) void attn_kernel(
        const unsigned short* __restrict__ qkvg,
        const float* __restrict__ bias_t,
        unsigned short* __restrict__ og16) {
    __shared__ __align__(16) unsigned short k_lds[256 * KP];
    __shared__ __align__(16) unsigned short vT[32 * VP];
    int head = blockIdx.x >> 8;
    int brow = blockIdx.x & 255;
    int t = threadIdx.x;
    const unsigned short* qsec = qkvg + (size_t)(0 + head) * SEC;
    const unsigned short* ksec = qkvg + (size_t)(4 + head) * SEC;
    const unsigned short* vsec = qkvg + (size_t)(8 + head) * SEC;
    const unsigned short* gsec = qkvg + (size_t)(12 + head) * SEC;
    {
        const unsigned short* ksrc = ksec + (size_t)(brow * 256 + t) * 32;
        #pragma unroll
        for (int i = 0; i < 4; ++i)
            *reinterpret_cast<bf16x8*>(&k_lds[t * KP + i * 8]) =
                *reinterpret_cast<const bf16x8*>(ksrc + i * 8);
        const unsigned short* vsrc = vsec + (size_t)(brow * 256 + t) * 32;
        unsigned short vv[32];
        #pragma unroll
        for (int i = 0; i < 4; ++i)
            *reinterpret_cast<bf16x8*>(&vv[i * 8]) =
                *reinterpret_cast<const bf16x8*>(vsrc + i * 8);
        // permuted k-position: k=t -> p = s8*32 + lg*8 + jhi*4 + jr
        int p = ((t >> 5) << 5) + (((t >> 2) & 3) << 3) + (((t >> 4) & 1) << 2) + (t & 3);
        #pragma unroll
        for (int d = 0; d < 32; ++d) vT[d * VP + p] = vv[d];
    }
    __syncthreads();
    int wave = t >> 6, lane = t & 63;
    int lg = lane >> 4, lr = lane & 15;
    const floatx4 fzero = {0.f, 0.f, 0.f, 0.f};

    for (int it = 0; it < 4; ++it) {
        int q0 = it * 64 + wave * 16;
        bf16x8 qf = *reinterpret_cast<const bf16x8*>(
            qsec + (size_t)(brow * 256 + q0 + lr) * 32 + lg * 8);
        // bias fragment doubles as the MFMA C-init: C[k=kt*16+lg*4+r][q=lr]
        const float* bb = bias_t + head * 65536 + (size_t)lg * 1024 + (q0 + lr) * 4;
        floatx4 sc[16];
        #pragma unroll
        for (int kt = 0; kt < 16; ++kt)
            sc[kt] = *reinterpret_cast<const floatx4*>(bb + kt * 4096);
        #pragma unroll
        for (int kt = 0; kt < 16; ++kt) {
            bf16x8 kf = *reinterpret_cast<const bf16x8*>(&k_lds[(kt * 16 + lr) * KP + lg * 8]);
            sc[kt] = MFMA(kf, qf, sc[kt]);   // swapped: C[k][q], bias pre-added
        }
        float rs = 0.f;
        unsigned int pk[32];
        #pragma unroll
        for (int kt = 0; kt < 16; ++kt) {
            float p0 = exp2_hw(sc[kt][0]);
            float p1 = exp2_hw(sc[kt][1]);
            float p2 = exp2_hw(sc[kt][2]);
            float p3 = exp2_hw(sc[kt][3]);
            rs += (p0 + p1) + (p2 + p3);
            pk[kt * 2]     = cvt_pk_bf16(p0, p1);
            pk[kt * 2 + 1] = cvt_pk_bf16(p2, p3);
        }
        rs += __shfl_xor(rs, 16);
        rs += __shfl_xor(rs, 32);
        float rinv = rcp_hw(rs);   // per thread: denom for q = lr
        // PV with permuted k-axis: A-frag = own pk registers
        floatx4 o0 = fzero, o1 = fzero;
        #pragma unroll
        for (int s8 = 0; s8 < 8; ++s8) {
            union { unsigned int u[4]; bf16x8 v; } pa;
            pa.u[0] = pk[s8 * 4];
            pa.u[1] = pk[s8 * 4 + 1];
            pa.u[2] = pk[s8 * 4 + 2];
            pa.u[3] = pk[s8 * 4 + 3];
            bf16x8 v0 = *reinterpret_cast<const bf16x8*>(&vT[lr * VP + s8 * 32 + lg * 8]);
            bf16x8 v1 = *reinterpret_cast<const bf16x8*>(&vT[(16 + lr) * VP + s8 * 32 + lg * 8]);
            o0 = MFMA(pa.v, v0, o0);
            o1 = MFMA(pa.v, v1, o1);
        }
        // epilogue: normalize (denom of q=lg*4+r via shfl), gate, store
        float rq[4];
        #pragma unroll
        for (int rr = 0; rr < 4; ++rr) rq[rr] = __shfl(rinv, lg * 4 + rr);
        #pragma unroll
        for (int n = 0; n < 2; ++n) {
            floatx4 ov = (n == 0) ? o0 : o1;
            #pragma unroll
            for (int rr = 0; rr < 4; ++rr) {
                int qrow = q0 + lg * 4 + rr;
                int col = head * 32 + n * 16 + lr;
                float val = ov[rr] * rq[rr];
                float gv = bf2f(gsec[(size_t)(brow * 256 + qrow) * 32 + n * 16 + lr]);
                og16[((size_t)(brow * 256 + qrow)) * 128 + col] = f2bf(val * gv);
            }
        }
    }
}

// ---------------------------------------------------------------------------
// Kernel 4: out[m][n] = sum_k og16[m][k] * wo16[n][k]  (verbatim).
// ---------------------------------------------------------------------------
__global__ __launch_bounds__(256) void out_gemm(
        const unsigned short* __restrict__ og16,
        const unsigned short* __restrict__ wo16,
        float* __restrict__ out) {
    __shared__ __align__(16) unsigned short As[128 * GP];
    __shared__ __align__(16) unsigned short Bs[128 * GP];
    int mt = blockIdx.x;
    int t = threadIdx.x;
    {
        int r = t >> 1, c0 = (t & 1) * 64;
        const unsigned short* srca = og16 + (size_t)(mt * 128 + r) * 128 + c0;
        const unsigned short* srcb = wo16 + (size_t)r * 128 + c0;
        #pragma unroll
        for (int i = 0; i < 8; ++i) {
            *reinterpret_cast<bf16x8*>(&As[r * GP + c0 + i * 8]) =
                *reinterpret_cast<const bf16x8*>(srca + i * 8);
            *reinterpret_cast<bf16x8*>(&Bs[r * GP + c0 + i * 8]) =
                *reinterpret_cast<const bf16x8*>(srcb + i * 8);
        }
    }
    __syncthreads();
    int wave = t >> 6, lane = t & 63;
    int m0 = (wave >> 1) * 64, n0 = (wave & 1) * 64;
    int lg = lane >> 4, lr = lane & 15;
    floatx4 acc[4][4] = {};
    #pragma unroll
    for (int ks = 0; ks < 4; ++ks) {
        bf16x8 a[4], b[4];
        #pragma unroll
        for (int i = 0; i < 4; ++i) {
            a[i] = *reinterpret_cast<const bf16x8*>(&As[(m0 + i * 16 + lr) * GP + ks * 32 + lg * 8]);
            b[i] = *reinterpret_cast<const bf16x8*>(&Bs[(n0 + i * 16 + lr) * GP + ks * 32 + lg * 8]);
        }
        #pragma unroll
        for (int i = 0; i < 4; ++i)
            #pragma unroll
            for (int j = 0; j < 4; ++j)
                acc[i][j] = MFMA(a[i], b[j], acc[i][j]);
    }
    #pragma unroll
    for (int i = 0; i < 4; ++i)
        #pragma unroll
        for (int j = 0; j < 4; ++j) {
            int nc = n0 + j * 16 + lr;
            #pragma unroll
            for (int rr = 0; rr < 4; ++rr) {
                int mr = mt * 128 + m0 + i * 16 + lg * 4 + rr;
                out[(size_t)mr * 128 + nc] = acc[i][j][rr];
            }
        }
}

// ---------------------------------------------------------------------------
extern "C" void kernel_launch(void* const* d_in, const int* in_sizes, int n_in,
                              void* d_out, int out_size, void* d_ws, size_t ws_size,
                              hipStream_t stream) {
    const float* x      = (const float*)d_in[0];
    const float* ln_w   = (const float*)d_in[1];
    const float* ln_b   = (const float*)d_in[2];
    const float* w_bias = (const float*)d_in[3];
    const float* w_q    = (const float*)d_in[4];
    const float* w_k    = (const float*)d_in[5];
    const float* w_v    = (const float*)d_in[6];
    const float* w_g    = (const float*)d_in[7];
    const float* w_o    = (const float*)d_in[8];

    char* ws = (char*)d_ws;
    unsigned short* og16   = (unsigned short*)(ws);                       // 16 MB
    unsigned short* qkvg   = (unsigned short*)(ws + 16777216);            // 64 MB
    float*          bias_t = (float*)(ws + 16777216 + 67108864);          // 1 MB
    unsigned short* wcat16 = (unsigned short*)(ws + 16777216 + 67108864 + 1048576);
    unsigned short* wo16   = (unsigned short*)(ws + 16777216 + 67108864 + 1048576 + 131072);
    float* out = (float*)d_out;

    hipLaunchKernelGGL(wconv_kernel, dim3(256), dim3(256), 0, stream,
                       w_q, w_k, w_v, w_g, w_o, wcat16, wo16);
    hipLaunchKernelGGL(proj_gemm, dim3(2048), dim3(512), 0, stream,
                       x, ln_w, ln_b, w_bias, wcat16, qkvg, bias_t);
    hipLaunchKernelGGL(attn_kernel, dim3(1024), dim3(256), 0, stream,
                       qkvg, bias_t, og16);
    hipLaunchKernelGGL(out_gemm, dim3(512), dim3(256), 0, stream,
                       og16, wo16, out);
}

// Round 24
// 83.091 us; speedup vs baseline: 1.0406x; 1.0406x over previous
//
#include <hip/hip_runtime.h>
#include <math.h>

#define S_DIM 256
#define D_DIM 128
#define NHEAD 4
#define HD_DIM 32
#define SEC 2097152   // 65536 tokens * 32 (shorts per section)

typedef __attribute__((ext_vector_type(8))) short bf16x8;
typedef __attribute__((ext_vector_type(4))) float floatx4;

#define MFMA(a, b, c) __builtin_amdgcn_mfma_f32_16x16x32_bf16(a, b, c, 0, 0, 0)

#define LOG2E 1.4426950408889634f

__device__ inline float exp2_hw(float x) {        // v_exp_f32 = 2^x
    float r;
    asm("v_exp_f32 %0, %1" : "=v"(r) : "v"(x));
    return r;
}
__device__ inline float rcp_hw(float x) {         // v_rcp_f32 ~1ulp
    float r;
    asm("v_rcp_f32 %0, %1" : "=v"(r) : "v"(x));
    return r;
}
__device__ inline unsigned int cvt_pk_bf16(float lo, float hi) {  // RNE pack
    unsigned int r;
    asm("v_cvt_pk_bf16_f32 %0, %1, %2" : "=v"(r) : "v"(lo), "v"(hi));
    return r;
}
__device__ inline unsigned short f2bf(float v) {
    return (unsigned short)(cvt_pk_bf16(v, v) & 0xffffu);
}
__device__ inline float bf2f(unsigned short s) {
    return __uint_as_float(((unsigned int)s) << 16);
}

// ---------------------------------------------------------------------------
// Kernel 1: weight convert to bf16.
// ---------------------------------------------------------------------------
__global__ __launch_bounds__(256) void wconv_kernel(
        const float* __restrict__ wq, const float* __restrict__ wk,
        const float* __restrict__ wv, const float* __restrict__ wg,
        const float* __restrict__ wo,
        unsigned short* __restrict__ wcat16, unsigned short* __restrict__ wo16) {
    int idx = blockIdx.x * 256 + threadIdx.x;
    if (idx < 65536) {
        int r = idx >> 7, c = idx & 127;
        float v;
        if (r < 128)      v = wq[idx] * (0.17677669529663687f * LOG2E);
        else if (r < 256) v = wk[(r - 128) * 128 + c];
        else if (r < 384) v = wv[(r - 256) * 128 + c];
        else              v = wg[(r - 384) * 128 + c];
        wcat16[idx] = f2bf(v);
    }
    if (idx < 16384) wo16[idx] = f2bf(wo[idx]);
}

// ---------------------------------------------------------------------------
// Kernel 2: fused LN + projection GEMM + fp32 bias GEMV (R19-exact:
// (512,4), 64-row tile, wave owns 64 cols, B direct from L2, epilogue
// LDS-transpose wide stores to head-blocked qkvg2[(type*4+head)][tok][32]).
// ---------------------------------------------------------------------------
#define GP 136
#define XS 68   // transpose scratch row stride (shorts)
__global__ __launch_bounds__(512, 4) void proj_gemm(
        const float* __restrict__ x,
        const float* __restrict__ ln_w, const float* __restrict__ ln_b,
        const float* __restrict__ w_bias,
        const unsigned short* __restrict__ wcat16,
        unsigned short* __restrict__ qkvg, float* __restrict__ bias_t) {
    __shared__ __align__(16) unsigned short As[64 * GP];
    int mt = blockIdx.x;          // 64-row tile index
    int t = threadIdx.x;          // 0..511
    int r = t >> 3, c0 = (t & 7) * 16;
    {   // LN staging: 8 threads per row, 16 cols each
        const float* xr = x + (size_t)(mt * 64 + r) * 128 + c0;
        float4 xv[4];
        float s = 0.f, sq = 0.f;
        #pragma unroll
        for (int i = 0; i < 4; ++i) {
            xv[i] = *reinterpret_cast<const float4*>(xr + i * 4);
            s += (xv[i].x + xv[i].y) + (xv[i].z + xv[i].w);
            sq += (xv[i].x * xv[i].x + xv[i].y * xv[i].y)
                + (xv[i].z * xv[i].z + xv[i].w * xv[i].w);
        }
        s += __shfl_xor(s, 1);  s += __shfl_xor(s, 2);  s += __shfl_xor(s, 4);
        sq += __shfl_xor(sq, 1); sq += __shfl_xor(sq, 2); sq += __shfl_xor(sq, 4);
        float mu = s * (1.0f / 128.0f);
        float rstd = rsqrtf(sq * (1.0f / 128.0f) - mu * mu + 1e-5f);
        float pb[4] = {0.f, 0.f, 0.f, 0.f};
        #pragma unroll
        for (int i = 0; i < 4; ++i) {
            float4 wv4 = *reinterpret_cast<const float4*>(ln_w + c0 + i * 4);
            float4 bv4 = *reinterpret_cast<const float4*>(ln_b + c0 + i * 4);
            float h0 = (xv[i].x - mu) * rstd * wv4.x + bv4.x;
            float h1 = (xv[i].y - mu) * rstd * wv4.y + bv4.y;
            float h2 = (xv[i].z - mu) * rstd * wv4.z + bv4.z;
            float h3 = (xv[i].w - mu) * rstd * wv4.w + bv4.w;
            unsigned int* dst = reinterpret_cast<unsigned int*>(&As[r * GP + c0 + i * 4]);
            dst[0] = cvt_pk_bf16(h0, h1);
            dst[1] = cvt_pk_bf16(h2, h3);
            #pragma unroll
            for (int hh = 0; hh < 4; ++hh) {
                float4 wb4 = *reinterpret_cast<const float4*>(w_bias + hh * 128 + c0 + i * 4);
                pb[hh] += (h0 * wb4.x + h1 * wb4.y) + (h2 * wb4.z + h3 * wb4.w);
            }
        }
        #pragma unroll
        for (int hh = 0; hh < 4; ++hh) {
            pb[hh] += __shfl_xor(pb[hh], 1);
            pb[hh] += __shfl_xor(pb[hh], 2);
            pb[hh] += __shfl_xor(pb[hh], 4);
        }
        if ((t & 7) == 0) {
            int m = mt * 64 + r;
            int q = m >> 8;
            int k = m & 255;
            #pragma unroll
            for (int hh = 0; hh < 4; ++hh)
                bias_t[hh * 65536 + (k >> 2) * 1024 + q * 4 + (k & 3)] = pb[hh] * LOG2E;
        }
    }
    __syncthreads();
    int wave = t >> 6, lane = t & 63;
    int lg = lane >> 4, lr = lane & 15;
    int n0 = wave * 64;                    // wave owns cols [n0, n0+64)
    floatx4 acc[4][4] = {};
    #pragma unroll
    for (int ks = 0; ks < 4; ++ks) {
        bf16x8 a[4], b[4];
        #pragma unroll
        for (int j = 0; j < 4; ++j)
            b[j] = *reinterpret_cast<const bf16x8*>(
                wcat16 + (size_t)(n0 + j * 16 + lr) * 128 + ks * 32 + lg * 8);
        #pragma unroll
        for (int i = 0; i < 4; ++i)
            a[i] = *reinterpret_cast<const bf16x8*>(&As[(i * 16 + lr) * GP + ks * 32 + lg * 8]);
        #pragma unroll
        for (int i = 0; i < 4; ++i)
            #pragma unroll
            for (int j = 0; j < 4; ++j)
                acc[i][j] = MFMA(a[i], b[j], acc[i][j]);
    }
    __syncthreads();                       // all waves done reading As
    bool is_g = (wave >= 6);               // cols 384..511 -> type 3
    unsigned short* xs = As + wave * (16 * XS);   // per-wave scratch
    int rrow = lane >> 3, rc8 = (lane & 7) * 8;   // read/store mapping
    int col = n0 + rc8;                    // 512-col space
    int sec = (col >> 7) * 4 + ((col >> 5) & 3);  // type*4 + head
    int dd  = col & 31;                    // d offset within head
    #pragma unroll
    for (int i = 0; i < 4; ++i) {
        #pragma unroll
        for (int j = 0; j < 4; ++j)
            #pragma unroll
            for (int rr = 0; rr < 4; ++rr) {
                float v = acc[i][j][rr];
                if (is_g) v = rcp_hw(1.0f + exp2_hw(-LOG2E * v));
                xs[(lg * 4 + rr) * XS + j * 16 + lr] = f2bf(v);
            }
        #pragma unroll
        for (int p = 0; p < 2; ++p) {
            int row = p * 8 + rrow;
            uint2 lo = *reinterpret_cast<const uint2*>(&xs[row * XS + rc8]);
            uint2 hi = *reinterpret_cast<const uint2*>(&xs[row * XS + rc8 + 4]);
            uint4 vv = {lo.x, lo.y, hi.x, hi.y};
            size_t m = (size_t)(mt * 64 + i * 16 + row);
            *reinterpret_cast<uint4*>(
                &qkvg[(size_t)sec * SEC + m * 32 + dd]) = vv;
        }
    }
}

// ---------------------------------------------------------------------------
// Kernel 3: attention (R19-exact: swapped QK^T + k-permutation, bias as
// MFMA C-init from packed-transposed fp32, exp2 path, P in registers,
// V pre-permuted in LDS, head-blocked qkvg2 reads, gating in epilogue).
// ---------------------------------------------------------------------------
#define KP 40    // k_lds row stride (bf16)
#define VP 260   // vT row stride (bf16)
__global__ __launch_bounds__(256) void attn_kernel(
        const unsigned short* __restrict__ qkvg,
        const float* __restrict__ bias_t,
        unsigned short* __restrict__ og16) {
    __shared__ __align__(16) unsigned short k_lds[256 * KP];
    __shared__ __align__(16) unsigned short vT[32 * VP];
    int head = blockIdx.x >> 8;
    int brow = blockIdx.x & 255;
    int t = threadIdx.x;
    const unsigned short* qsec = qkvg + (size_t)(0 + head) * SEC;
    const unsigned short* ksec = qkvg + (size_t)(4 + head) * SEC;
    const unsigned short* vsec = qkvg + (size_t)(8 + head) * SEC;
    const unsigned short* gsec = qkvg + (size_t)(12 + head) * SEC;
    {
        const unsigned short* ksrc = ksec + (size_t)(brow * 256 + t) * 32;
        #pragma unroll
        for (int i = 0; i < 4; ++i)
            *reinterpret_cast<bf16x8*>(&k_lds[t * KP + i * 8]) =
                *reinterpret_cast<const bf16x8*>(ksrc + i * 8);
        const unsigned short* vsrc = vsec + (size_t)(brow * 256 + t) * 32;
        unsigned short vv[32];
        #pragma unroll
        for (int i = 0; i < 4; ++i)
            *reinterpret_cast<bf16x8*>(&vv[i * 8]) =
                *reinterpret_cast<const bf16x8*>(vsrc + i * 8);
        // permuted k-position: k=t -> p = s8*32 + lg*8 + jhi*4 + jr
        int p = ((t >> 5) << 5) + (((t >> 2) & 3) << 3) + (((t >> 4) & 1) << 2) + (t & 3);
        #pragma unroll
        for (int d = 0; d < 32; ++d) vT[d * VP + p] = vv[d];
    }
    __syncthreads();
    int wave = t >> 6, lane = t & 63;
    int lg = lane >> 4, lr = lane & 15;
    const floatx4 fzero = {0.f, 0.f, 0.f, 0.f};

    for (int it = 0; it < 4; ++it) {
        int q0 = it * 64 + wave * 16;
        bf16x8 qf = *reinterpret_cast<const bf16x8*>(
            qsec + (size_t)(brow * 256 + q0 + lr) * 32 + lg * 8);
        // bias fragment doubles as the MFMA C-init: C[k=kt*16+lg*4+r][q=lr]
        const float* bb = bias_t + head * 65536 + (size_t)lg * 1024 + (q0 + lr) * 4;
        floatx4 sc[16];
        #pragma unroll
        for (int kt = 0; kt < 16; ++kt)
            sc[kt] = *reinterpret_cast<const floatx4*>(bb + kt * 4096);
        #pragma unroll
        for (int kt = 0; kt < 16; ++kt) {
            bf16x8 kf = *reinterpret_cast<const bf16x8*>(&k_lds[(kt * 16 + lr) * KP + lg * 8]);
            sc[kt] = MFMA(kf, qf, sc[kt]);   // swapped: C[k][q], bias pre-added
        }
        float rs = 0.f;
        unsigned int pk[32];
        #pragma unroll
        for (int kt = 0; kt < 16; ++kt) {
            float p0 = exp2_hw(sc[kt][0]);
            float p1 = exp2_hw(sc[kt][1]);
            float p2 = exp2_hw(sc[kt][2]);
            float p3 = exp2_hw(sc[kt][3]);
            rs += (p0 + p1) + (p2 + p3);
            pk[kt * 2]     = cvt_pk_bf16(p0, p1);
            pk[kt * 2 + 1] = cvt_pk_bf16(p2, p3);
        }
        rs += __shfl_xor(rs, 16);
        rs += __shfl_xor(rs, 32);
        float rinv = rcp_hw(rs);   // per thread: denom for q = lr
        // PV with permuted k-axis: A-frag = own pk registers
        floatx4 o0 = fzero, o1 = fzero;
        #pragma unroll
        for (int s8 = 0; s8 < 8; ++s8) {
            union { unsigned int u[4]; bf16x8 v; } pa;
            pa.u[0] = pk[s8 * 4];
            pa.u[1] = pk[s8 * 4 + 1];
            pa.u[2] = pk[s8 * 4 + 2];
            pa.u[3] = pk[s8 * 4 + 3];
            bf16x8 v0 = *reinterpret_cast<const bf16x8*>(&vT[lr * VP + s8 * 32 + lg * 8]);
            bf16x8 v1 = *reinterpret_cast<const bf16x8*>(&vT[(16 + lr) * VP + s8 * 32 + lg * 8]);
            o0 = MFMA(pa.v, v0, o0);
            o1 = MFMA(pa.v, v1, o1);
        }
        // epilogue: normalize (denom of q=lg*4+r via shfl), gate, store
        float rq[4];
        #pragma unroll
        for (int rr = 0; rr < 4; ++rr) rq[rr] = __shfl(rinv, lg * 4 + rr);
        #pragma unroll
        for (int n = 0; n < 2; ++n) {
            floatx4 ov = (n == 0) ? o0 : o1;
            #pragma unroll
            for (int rr = 0; rr < 4; ++rr) {
                int qrow = q0 + lg * 4 + rr;
                int col = head * 32 + n * 16 + lr;
                float val = ov[rr] * rq[rr];
                float gv = bf2f(gsec[(size_t)(brow * 256 + qrow) * 32 + n * 16 + lr]);
                og16[((size_t)(brow * 256 + qrow)) * 128 + col] = f2bf(val * gv);
            }
        }
    }
}

// ---------------------------------------------------------------------------
// Kernel 4: out[m][n] = sum_k og16[m][k] * wo16[n][k].
// ---------------------------------------------------------------------------
__global__ __launch_bounds__(256) void out_gemm(
        const unsigned short* __restrict__ og16,
        const unsigned short* __restrict__ wo16,
        float* __restrict__ out) {
    __shared__ __align__(16) unsigned short As[128 * GP];
    __shared__ __align__(16) unsigned short Bs[128 * GP];
    int mt = blockIdx.x;
    int t = threadIdx.x;
    {
        int r = t >> 1, c0 = (t & 1) * 64;
        const unsigned short* srca = og16 + (size_t)(mt * 128 + r) * 128 + c0;
        const unsigned short* srcb = wo16 + (size_t)r * 128 + c0;
        #pragma unroll
        for (int i = 0; i < 8; ++i) {
            *reinterpret_cast<bf16x8*>(&As[r * GP + c0 + i * 8]) =
                *reinterpret_cast<const bf16x8*>(srca + i * 8);
            *reinterpret_cast<bf16x8*>(&Bs[r * GP + c0 + i * 8]) =
                *reinterpret_cast<const bf16x8*>(srcb + i * 8);
        }
    }
    __syncthreads();
    int wave = t >> 6, lane = t & 63;
    int m0 = (wave >> 1) * 64, n0 = (wave & 1) * 64;
    int lg = lane >> 4, lr = lane & 15;
    floatx4 acc[4][4] = {};
    #pragma unroll
    for (int ks = 0; ks < 4; ++ks) {
        bf16x8 a[4], b[4];
        #pragma unroll
        for (int i = 0; i < 4; ++i) {
            a[i] = *reinterpret_cast<const bf16x8*>(&As[(m0 + i * 16 + lr) * GP + ks * 32 + lg * 8]);
            b[i] = *reinterpret_cast<const bf16x8*>(&Bs[(n0 + i * 16 + lr) * GP + ks * 32 + lg * 8]);
        }
        #pragma unroll
        for (int i = 0; i < 4; ++i)
            #pragma unroll
            for (int j = 0; j < 4; ++j)
                acc[i][j] = MFMA(a[i], b[j], acc[i][j]);
    }
    #pragma unroll
    for (int i = 0; i < 4; ++i)
        #pragma unroll
        for (int j = 0; j < 4; ++j) {
            int nc = n0 + j * 16 + lr;
            #pragma unroll
            for (int rr = 0; rr < 4; ++rr) {
                int mr = mt * 128 + m0 + i * 16 + lg * 4 + rr;
                out[(size_t)mr * 128 + nc] = acc[i][j][rr];
            }
        }
}

// ---------------------------------------------------------------------------
extern "C" void kernel_launch(void* const* d_in, const int* in_sizes, int n_in,
                              void* d_out, int out_size, void* d_ws, size_t ws_size,
                              hipStream_t stream) {
    const float* x      = (const float*)d_in[0];
    const float* ln_w   = (const float*)d_in[1];
    const float* ln_b   = (const float*)d_in[2];
    const float* w_bias = (const float*)d_in[3];
    const float* w_q    = (const float*)d_in[4];
    const float* w_k    = (const float*)d_in[5];
    const float* w_v    = (const float*)d_in[6];
    const float* w_g    = (const float*)d_in[7];
    const float* w_o    = (const float*)d_in[8];

    char* ws = (char*)d_ws;
    unsigned short* og16   = (unsigned short*)(ws);                       // 16 MB
    unsigned short* qkvg   = (unsigned short*)(ws + 16777216);            // 64 MB
    float*          bias_t = (float*)(ws + 16777216 + 67108864);          // 1 MB
    unsigned short* wcat16 = (unsigned short*)(ws + 16777216 + 67108864 + 1048576);
    unsigned short* wo16   = (unsigned short*)(ws + 16777216 + 67108864 + 1048576 + 131072);
    float* out = (float*)d_out;

    hipLaunchKernelGGL(wconv_kernel, dim3(256), dim3(256), 0, stream,
                       w_q, w_k, w_v, w_g, w_o, wcat16, wo16);
    hipLaunchKernelGGL(proj_gemm, dim3(1024), dim3(512), 0, stream,
                       x, ln_w, ln_b, w_bias, wcat16, qkvg, bias_t);
    hipLaunchKernelGGL(attn_kernel, dim3(1024), dim3(256), 0, stream,
                       qkvg, bias_t, og16);
    hipLaunchKernelGGL(out_gemm, dim3(512), dim3(256), 0, stream,
                       og16, wo16, out);
}